// Round 1
// baseline (366.636 us; speedup 1.0000x reference)
//
#include <hip/hip_runtime.h>
#include <math.h>

#define DIMC 16
#define KB 8
// c = (XY_MAX - XY_MIN) - K*MIN_BW = 2 - 8*0.001
#define C_SCALE 1.992f
#define MIN_BW 0.001f
#define MIN_KS 0.001f

#define LOG2E 1.44269504088896340736f
#define LN2   0.69314718055994530942f

__device__ __forceinline__ float fast_exp(float v) {
    return __builtin_amdgcn_exp2f(v * LOG2E);          // v_exp_f32
}
__device__ __forceinline__ float fast_log(float v) {
    return __builtin_amdgcn_logf(v) * LN2;             // v_log_f32
}
__device__ __forceinline__ float fast_rcp(float v) {
    return __builtin_amdgcn_rcpf(v);                   // v_rcp_f32
}

// softplus(v) = max(v,0) + log(1 + exp(-|v|)); 1+e in [1,2] so fast_log is safe
__device__ __forceinline__ float softplus_f(float v) {
    float e = fast_exp(-fabsf(v));
    return fmaxf(v, 0.0f) + fast_log(1.0f + e);
}

// Per-transform parameter block, fully resident in VGPRs.
struct TP {
    float w[KB];
    float h[KB];
    float s[KB - 1];
    float sh;
};

__device__ __forceinline__ void load8(const float* __restrict__ p, float* dst) {
    float4 a = ((const float4*)p)[0];
    float4 b = ((const float4*)p)[1];
    dst[0] = a.x; dst[1] = a.y; dst[2] = a.z; dst[3] = a.w;
    dst[4] = b.x; dst[5] = b.y; dst[6] = b.z; dst[7] = b.w;
}

__device__ __forceinline__ float transform_step(float x, const TP& p, float& ladJsum) {
    // forward periodic shift: mod(x+shift+1, 2) - 1; x in [-1,1), shift in [0,1)
    {
        float v = x + p.sh + 1.0f;
        if (v >= 2.0f) v -= 2.0f;
        x = v - 1.0f;
    }

    float wv[KB], hv[KB];
    // softmax(w)*c + MIN_BW -> widths; softmax(h)*c + MIN_BW -> heights
    float mxw = p.w[0], mxh = p.h[0];
    #pragma unroll
    for (int j = 1; j < KB; ++j) { mxw = fmaxf(mxw, p.w[j]); mxh = fmaxf(mxh, p.h[j]); }
    float sw = 0.0f, sh2 = 0.0f;
    #pragma unroll
    for (int j = 0; j < KB; ++j) { wv[j] = fast_exp(p.w[j] - mxw); sw  += wv[j]; }
    #pragma unroll
    for (int j = 0; j < KB; ++j) { hv[j] = fast_exp(p.h[j] - mxh); sh2 += hv[j]; }
    float iw = C_SCALE * fast_rcp(sw);
    float ih = C_SCALE * fast_rcp(sh2);
    #pragma unroll
    for (int j = 0; j < KB; ++j) { wv[j] = wv[j] * iw + MIN_BW; hv[j] = hv[j] * ih + MIN_BW; }

    // Fused cumsum + bin search + register-select gather.
    // Also selects the two slope inputs (s[idx-1], s[idx]) in-register,
    // replacing the former data-dependent global gather of S.
    float xk = -1.0f, yk = -1.0f;        // running knot position
    float x0 = -1.0f, y0 = -1.0f;
    float wk = wv[0], hk = hv[0];
    float sA = p.s[0], sB = p.s[0];      // sB valid for idx=0 (d1 = sp(s[0]))
    bool first = true, last = false;     // idx==0 / idx==KB-1
    #pragma unroll
    for (int j = 1; j < KB; ++j) {
        xk += wv[j - 1];
        yk += hv[j - 1];
        bool ge = (x >= xk);
        if (j == 1)      first = !ge;
        if (j == KB - 1) last  = ge;
        x0 = ge ? xk    : x0;
        y0 = ge ? yk    : y0;
        wk = ge ? wv[j] : wk;
        hk = ge ? hv[j] : hk;
        sA = ge ? p.s[j - 1] : sA;
        sB = ge ? p.s[(j < KB - 1) ? j : KB - 2] : sB;   // j=KB-1: unused (d1=1)
    }
    // knot slopes: d[0]=d[K]=1, interior = softplus(s)+MIN_KS
    float d0 = first ? 1.0f : softplus_f(sA) + MIN_KS;
    float d1 = last  ? 1.0f : softplus_f(sB) + MIN_KS;

    float rwk = fast_rcp(wk);
    float sk  = hk * rwk;
    float tt  = (x - x0) * rwk;
    float omt = 1.0f - tt;
    float a2  = d1 + d0 - 2.0f * sk;
    float den = sk + a2 * tt * omt;
    float rden = fast_rcp(den);
    float y   = y0 + hk * (sk * tt * tt + d0 * tt * omt) * rden;
    float num = d1 * tt * tt + 2.0f * sk * tt * omt + d0 * omt * omt;
    // ladJ = 2 log sk + log num - 2 log den = log(sk^2 * num * rden^2)
    float skr = sk * rden;
    ladJsum += fast_log(skr * skr * num);

    // inverse periodic shift: mod(y - shift + 1, 2) - 1, arg in (-1, 2]
    {
        float u = y - p.sh + 1.0f;
        if (u < 0.0f)  u += 2.0f;
        if (u >= 2.0f) u -= 2.0f;
        return u - 1.0f;
    }
}

__global__ __launch_bounds__(256) void spline_coupling_kernel(
    const float* __restrict__ X,
    const float* __restrict__ W,
    const float* __restrict__ H,
    const float* __restrict__ S,
    const float* __restrict__ SH,
    float* __restrict__ OUT,
    int m)
{
    const int total = m * DIMC;
    const int gid = blockIdx.x * blockDim.x + threadIdx.x;
    if (gid >= total) return;
    const int row = gid >> 4;   // / DIMC
    const int d   = gid & 15;   // % DIMC

    const size_t b0 = (size_t)row;
    const size_t b1 = (size_t)m + (size_t)row;

    // ---- Issue EVERY load up front: 25 VMEM ops in flight per thread,
    //      one memory-latency exposure instead of four serialized ones. ----
    TP p0, p1;
    float x = X[gid];
    load8(W + b0 * (DIMC * KB) + d * KB, p0.w);
    load8(H + b0 * (DIMC * KB) + d * KB, p0.h);
    load8(W + b1 * (DIMC * KB) + d * KB, p1.w);
    load8(H + b1 * (DIMC * KB) + d * KB, p1.h);
    {
        const float* s0p = S + b0 * (DIMC * (KB - 1)) + d * (KB - 1);
        const float* s1p = S + b1 * (DIMC * (KB - 1)) + d * (KB - 1);
        #pragma unroll
        for (int j = 0; j < KB - 1; ++j) { p0.s[j] = s0p[j]; p1.s[j] = s1p[j]; }
    }
    p0.sh = SH[b0 * DIMC + d];
    p1.sh = SH[b1 * DIMC + d];

    float ladJsum = 0.0f;
    x = transform_step(x, p0, ladJsum);
    x = transform_step(x, p1, ladJsum);

    OUT[gid] = x;
    OUT[(size_t)total + gid] = ladJsum;
}

extern "C" void kernel_launch(void* const* d_in, const int* in_sizes, int n_in,
                              void* d_out, int out_size, void* d_ws, size_t ws_size,
                              hipStream_t stream) {
    const int total = in_sizes[0];        // m * DIM
    const int m = total / DIMC;
    const float* X  = (const float*)d_in[0];
    const float* W  = (const float*)d_in[1];
    const float* H  = (const float*)d_in[2];
    const float* S  = (const float*)d_in[3];
    const float* SH = (const float*)d_in[4];
    float* OUT = (float*)d_out;

    const int block = 256;
    const int grid = (total + block - 1) / block;
    spline_coupling_kernel<<<grid, block, 0, stream>>>(X, W, H, S, SH, OUT, m);
}

// Round 2
// 364.700 us; speedup vs baseline: 1.0053x; 1.0053x over previous
//
#include <hip/hip_runtime.h>
#include <math.h>
#include <stdint.h>

#define DIMC 16
#define KB 8
// c = (XY_MAX - XY_MIN) - K*MIN_BW = 2 - 8*0.001
#define C_SCALE 1.992f
#define MIN_BW 0.001f
#define MIN_KS 0.001f

#define LOG2E 1.44269504088896340736f
#define LN2   0.69314718055994530942f

#define RPB 16          // rows per 256-thread block
#define NCHUNK 24       // 1KB wave-chunks staged per transform (8 W + 8 H + 7 S + 1 SH)

// LDS layout, float offsets (24 KiB total)
#define LW   0          // 16 rows x 128 = 2048 floats
#define LH   2048       // 2048 floats
#define LS   4096       // 16 rows x 112 = 1792 floats
#define LSH  5888       // 16 rows x 16  = 256 floats
#define LTOT 6144

typedef const uint32_t __attribute__((address_space(1)))* gas_u32p;
typedef uint32_t __attribute__((address_space(3)))*       las_u32p;

__device__ __forceinline__ float fast_exp(float v) {
    return __builtin_amdgcn_exp2f(v * LOG2E);          // v_exp_f32
}
__device__ __forceinline__ float fast_log(float v) {
    return __builtin_amdgcn_logf(v) * LN2;             // v_log_f32
}
__device__ __forceinline__ float fast_rcp(float v) {
    return __builtin_amdgcn_rcpf(v);                   // v_rcp_f32
}

// softplus(v) = max(v,0) + log(1 + exp(-|v|)); 1+e in [1,2] so fast_log is safe
__device__ __forceinline__ float softplus_f(float v) {
    float e = fast_exp(-fabsf(v));
    return fmaxf(v, 0.0f) + fast_log(1.0f + e);
}

struct TP {
    float w[KB];
    float h[KB];
    float s[KB - 1];
    float sh;
};

__device__ __forceinline__ float transform_step(float x, const TP& p, float& ladJsum) {
    // forward periodic shift: mod(x+shift+1, 2) - 1; x in [-1,1), shift in [0,1)
    {
        float v = x + p.sh + 1.0f;
        if (v >= 2.0f) v -= 2.0f;
        x = v - 1.0f;
    }

    float wv[KB], hv[KB];
    float mxw = p.w[0], mxh = p.h[0];
    #pragma unroll
    for (int j = 1; j < KB; ++j) { mxw = fmaxf(mxw, p.w[j]); mxh = fmaxf(mxh, p.h[j]); }
    float sw = 0.0f, sh2 = 0.0f;
    #pragma unroll
    for (int j = 0; j < KB; ++j) { wv[j] = fast_exp(p.w[j] - mxw); sw  += wv[j]; }
    #pragma unroll
    for (int j = 0; j < KB; ++j) { hv[j] = fast_exp(p.h[j] - mxh); sh2 += hv[j]; }
    float iw = C_SCALE * fast_rcp(sw);
    float ih = C_SCALE * fast_rcp(sh2);
    #pragma unroll
    for (int j = 0; j < KB; ++j) { wv[j] = wv[j] * iw + MIN_BW; hv[j] = hv[j] * ih + MIN_BW; }

    // Fused cumsum + bin search + register-select gather (slopes selected in-register).
    float xk = -1.0f, yk = -1.0f;
    float x0 = -1.0f, y0 = -1.0f;
    float wk = wv[0], hk = hv[0];
    float sA = p.s[0], sB = p.s[0];
    bool first = true, last = false;
    #pragma unroll
    for (int j = 1; j < KB; ++j) {
        xk += wv[j - 1];
        yk += hv[j - 1];
        bool ge = (x >= xk);
        if (j == 1)      first = !ge;
        if (j == KB - 1) last  = ge;
        x0 = ge ? xk    : x0;
        y0 = ge ? yk    : y0;
        wk = ge ? wv[j] : wk;
        hk = ge ? hv[j] : hk;
        sA = ge ? p.s[j - 1] : sA;
        sB = ge ? p.s[(j < KB - 1) ? j : KB - 2] : sB;   // j=KB-1: unused (d1=1)
    }
    float d0 = first ? 1.0f : softplus_f(sA) + MIN_KS;
    float d1 = last  ? 1.0f : softplus_f(sB) + MIN_KS;

    float rwk = fast_rcp(wk);
    float sk  = hk * rwk;
    float tt  = (x - x0) * rwk;
    float omt = 1.0f - tt;
    float a2  = d1 + d0 - 2.0f * sk;
    float den = sk + a2 * tt * omt;
    float rden = fast_rcp(den);
    float y   = y0 + hk * (sk * tt * tt + d0 * tt * omt) * rden;
    float num = d1 * tt * tt + 2.0f * sk * tt * omt + d0 * omt * omt;
    float skr = sk * rden;
    ladJsum += fast_log(skr * skr * num);

    // inverse periodic shift: mod(y - shift + 1, 2) - 1, arg in (-1, 2]
    {
        float u = y - p.sh + 1.0f;
        if (u < 0.0f)  u += 2.0f;
        if (u >= 2.0f) u -= 2.0f;
        return u - 1.0f;
    }
}

// Cooperative global->LDS staging of one transform's parameter slabs.
// 24 chunks of 1KB; each wave handles 6; HW writes lane l at ldsbase + l*16B.
// All sources are 16B-aligned (row0 % 16 == 0; 128/112/16 floats per row).
__device__ __forceinline__ void stage_tiles(const float* __restrict__ Wb,
                                            const float* __restrict__ Hb,
                                            const float* __restrict__ Sb,
                                            const float* __restrict__ SHb,
                                            float* lds, int wid, int lane) {
    #pragma unroll
    for (int k = 0; k < NCHUNK / 4; ++k) {
        const int c = wid + k * 4;                 // wave-uniform
        const float* src;
        if (c < 8)       src = Wb  + c * 256;
        else if (c < 16) src = Hb  + (c - 8) * 256;
        else if (c < 23) src = Sb  + (c - 16) * 256;
        else             src = SHb;
        src += lane * 4;                           // per-lane global source
        __builtin_amdgcn_global_load_lds((gas_u32p)(const void*)src,
                                         (las_u32p)(void*)(lds + c * 256),
                                         16, 0, 0);
    }
}

__device__ __forceinline__ void read_params(TP& p, const float* lds, int rl, int d) {
    const float4* wp = (const float4*)(lds + LW + rl * 128 + d * 8);
    const float4* hp = (const float4*)(lds + LH + rl * 128 + d * 8);
    float4 a = wp[0], b = wp[1];
    p.w[0]=a.x; p.w[1]=a.y; p.w[2]=a.z; p.w[3]=a.w;
    p.w[4]=b.x; p.w[5]=b.y; p.w[6]=b.z; p.w[7]=b.w;
    a = hp[0]; b = hp[1];
    p.h[0]=a.x; p.h[1]=a.y; p.h[2]=a.z; p.h[3]=a.w;
    p.h[4]=b.x; p.h[5]=b.y; p.h[6]=b.z; p.h[7]=b.w;
    const float* sv = lds + LS + rl * 112 + d * 7;  // stride 7 dwords: bank-conflict-free
    #pragma unroll
    for (int j = 0; j < KB - 1; ++j) p.s[j] = sv[j];
    p.sh = lds[LSH + rl * 16 + d];
}

__global__ __launch_bounds__(256) void spline_coupling_kernel(
    const float* __restrict__ X,
    const float* __restrict__ W,
    const float* __restrict__ H,
    const float* __restrict__ S,
    const float* __restrict__ SH,
    float* __restrict__ OUT,
    int m)
{
    __shared__ float lds[LTOT];
    const int total = m * DIMC;
    const int tid  = threadIdx.x;
    const int row0 = blockIdx.x * RPB;
    const int rl   = tid >> 4;
    const int d    = tid & 15;
    const int row  = row0 + rl;
    const int gid  = row * DIMC + d;
    const int wid  = tid >> 6;
    const int lane = tid & 63;

    if (row0 + RPB <= m) {
        // ---------- fast path: full block of 16 rows ----------
        const size_t b0 = (size_t)row0;
        const size_t b1 = (size_t)m + (size_t)row0;

        float x = X[gid];
        float ladJ = 0.0f;

        // stage transform 0
        stage_tiles(W + b0 * 128, H + b0 * 128, S + b0 * 112, SH + b0 * 16,
                    lds, wid, lane);
        __syncthreads();                       // drains vmcnt -> LDS valid

        TP p0;
        read_params(p0, lds, rl, d);
        __syncthreads();                       // all reads done before overwrite

        // stage transform 1; HBM latency hides under transform-0 compute
        stage_tiles(W + b1 * 128, H + b1 * 128, S + b1 * 112, SH + b1 * 16,
                    lds, wid, lane);

        x = transform_step(x, p0, ladJ);

        __syncthreads();                       // transform-1 slabs valid

        TP p1;
        read_params(p1, lds, rl, d);
        x = transform_step(x, p1, ladJ);

        OUT[gid] = x;
        OUT[(size_t)total + gid] = ladJ;
    } else {
        // ---------- tail fallback: per-thread direct loads ----------
        if (row < m) {
            float x = X[gid];
            float ladJ = 0.0f;
            #pragma unroll
            for (int t = 0; t < 2; ++t) {
                const size_t base = (size_t)t * m + row;
                TP p;
                const float4* wp = (const float4*)(W + base * (DIMC * KB) + d * KB);
                const float4* hp = (const float4*)(H + base * (DIMC * KB) + d * KB);
                float4 a = wp[0], b = wp[1];
                p.w[0]=a.x; p.w[1]=a.y; p.w[2]=a.z; p.w[3]=a.w;
                p.w[4]=b.x; p.w[5]=b.y; p.w[6]=b.z; p.w[7]=b.w;
                a = hp[0]; b = hp[1];
                p.h[0]=a.x; p.h[1]=a.y; p.h[2]=a.z; p.h[3]=a.w;
                p.h[4]=b.x; p.h[5]=b.y; p.h[6]=b.z; p.h[7]=b.w;
                const float* sp = S + base * (DIMC * (KB - 1)) + d * (KB - 1);
                #pragma unroll
                for (int j = 0; j < KB - 1; ++j) p.s[j] = sp[j];
                p.sh = SH[base * DIMC + d];
                x = transform_step(x, p, ladJ);
            }
            OUT[gid] = x;
            OUT[(size_t)total + gid] = ladJ;
        }
    }
}

extern "C" void kernel_launch(void* const* d_in, const int* in_sizes, int n_in,
                              void* d_out, int out_size, void* d_ws, size_t ws_size,
                              hipStream_t stream) {
    const int total = in_sizes[0];        // m * DIM
    const int m = total / DIMC;
    const float* X  = (const float*)d_in[0];
    const float* W  = (const float*)d_in[1];
    const float* H  = (const float*)d_in[2];
    const float* S  = (const float*)d_in[3];
    const float* SH = (const float*)d_in[4];
    float* OUT = (float*)d_out;

    const int block = 256;
    const int grid = (m + RPB - 1) / RPB;
    spline_coupling_kernel<<<grid, block, 0, stream>>>(X, W, H, S, SH, OUT, m);
}